// Round 1
// 423.141 us; speedup vs baseline: 1.1434x; 1.1434x over previous
//
#include <hip/hip_runtime.h>
#include <hip/hip_bf16.h>
#include <stdint.h>

#define N_TOKENS   65536
#define IN_FEAT    512
#define OUT_FEAT   512
#define NUM_EXPERT 64
#define BM 128
#define BN 128
#define BK 32
#define SK 36                    // padded LDS row stride in shorts (BK+4): bank-conflict-free
#define K_STEPS (IN_FEAT / BK)   // 16
#define MAX_TILES 640            // true worst case: 512 + 64 = 576 tiles

// ws layout (int32 units), total footprint 139264 bytes (UNCHANGED from prev version):
//   [0..63]     counts
//   [64..127]   cursors
//   [128..192]  offsets (exclusive prefix, 65 entries)
//   [196]       dtype flag: 0 = buffers are bf16, 1 = buffers are fp32
//   [197]       tile_count
//   [200..1928) tiles: 3 ints each (expert, start, count), 576 entries
//   [2048..)    order as ushort[65536] (token ids sorted by expert) = 128 KB
#define WS_OFFS   128
#define WS_FLAG   196
#define WS_NTILES 197
#define WS_TILES  200
#define WS_ORDER  2048
#define WS_NEEDED (2048 * 4 + 131072)

typedef __attribute__((ext_vector_type(8))) short bf16x8;
typedef __attribute__((ext_vector_type(4))) float f32x4;

__device__ __forceinline__ float b2f(short v) {
    union { float f; unsigned u; } z;
    z.u = ((unsigned)(unsigned short)v) << 16;
    return z.f;
}

__device__ __forceinline__ unsigned pk2(float a, float b) {
    union { __hip_bfloat16 h; unsigned short u; } x, y;
    x.h = __float2bfloat16(a);
    y.h = __float2bfloat16(b);
    return ((unsigned)y.u << 16) | (unsigned)x.u;
}

__device__ __forceinline__ unsigned short f2bu(float a) {
    union { __hip_bfloat16 h; unsigned short u; } x;
    x.h = __float2bfloat16(a);
    return x.u;
}

// Fused: dtype-detect (1 wave) + zero counts/cursors.
// Classify inp's bit patterns: bf16-pair data has low-u16 exponent fields
// clustered in the "plausible magnitude" band; fp32 data's low-u16 is a
// uniform-random mantissa half. Data fixed per run -> same flag every call.
__global__ void k_setup(const unsigned* __restrict__ inw, int* __restrict__ ws) {
    int t = threadIdx.x;  // 128 threads
    ws[t] = 0;            // counts + cursors (does NOT touch WS_FLAG)
    if (t < 64) {
        int cnt = 0;
        #pragma unroll
        for (int i = 0; i < 16; ++i) {
            unsigned u = inw[t * 16 + i];
            unsigned lo = u & 0xFFFFu;
            unsigned ec = (lo >> 7) & 0xFFu;   // bf16 exponent field of low half
            if (lo == 0u || (ec >= 90u && ec <= 131u)) cnt++;
        }
        #pragma unroll
        for (int d = 32; d > 0; d >>= 1) cnt += __shfl_down(cnt, d, 64);
        if (t == 0) ws[WS_FLAG] = (cnt >= 512) ? 0 : 1;  // bf16 ~1000/1024, fp32 ~170/1024
    }
}

__global__ void k_hist(const int* __restrict__ gate, int* __restrict__ ws) {
    __shared__ int h[NUM_EXPERT];
    int t = threadIdx.x;
    if (t < NUM_EXPERT) h[t] = 0;
    __syncthreads();
    int base = blockIdx.x * 1024;
    #pragma unroll
    for (int k = 0; k < 4; ++k) {
        int g = gate[base + k * 256 + t] & 63;
        atomicAdd(&h[g], 1);
    }
    __syncthreads();
    if (t < NUM_EXPERT) atomicAdd(&ws[t], h[t]);
}

// single wave: prefix-scan counts, build tile descriptor list
__global__ void k_scan(int* ws) {
    int e = threadIdx.x;  // 0..63
    int c = ws[e];
    int pc = c;
    #pragma unroll
    for (int d = 1; d < 64; d <<= 1) {
        int v = __shfl_up(pc, d, 64);
        if (e >= d) pc += v;
    }
    int off = pc - c;  // exclusive prefix of token counts
    ws[WS_OFFS + e] = off;
    if (e == 63) ws[WS_OFFS + 64] = pc;

    int nt = (c + BM - 1) / BM;
    int tnt = nt;
    #pragma unroll
    for (int d = 1; d < 64; d <<= 1) {
        int v = __shfl_up(tnt, d, 64);
        if (e >= d) tnt += v;
    }
    int tbase = tnt - nt;
    for (int j = 0; j < nt; ++j) {
        int* t = ws + WS_TILES + (tbase + j) * 3;
        t[0] = e;
        t[1] = off + j * BM;
        int rem = c - j * BM;
        t[2] = rem < BM ? rem : BM;
    }
    if (e == 63) ws[WS_NTILES] = tnt;
}

// Block-aggregated scatter: ONE global atomic per (block, expert) — <=4096
// total instead of 65536 same-line device atomics (which serialize at the
// memory-side atomic unit: 64 cursors = 2 cache lines).
__global__ __launch_bounds__(256) void k_scatter(const int* __restrict__ gate,
                                                 int* __restrict__ ws) {
    __shared__ int lh[NUM_EXPERT];     // local histogram
    __shared__ int lbase[NUM_EXPERT];  // global slot base for this block
    __shared__ int lcur[NUM_EXPERT];   // local rank cursor
    int* cursors = ws + 64;
    const int* offsets = ws + WS_OFFS;
    unsigned short* order = (unsigned short*)(ws + WS_ORDER);
    int t = threadIdx.x;
    if (t < NUM_EXPERT) { lh[t] = 0; lcur[t] = 0; }
    __syncthreads();
    int base = blockIdx.x * 1024;
    int e[4];
    #pragma unroll
    for (int k = 0; k < 4; ++k) {
        e[k] = gate[base + k * 256 + t] & 63;
        atomicAdd(&lh[e[k]], 1);       // LDS atomic (fast)
    }
    __syncthreads();
    if (t < NUM_EXPERT) {
        int c = lh[t];
        int b = c ? atomicAdd(&cursors[t], c) : 0;  // one global atomic per expert
        lbase[t] = offsets[t] + b;
    }
    __syncthreads();
    #pragma unroll
    for (int k = 0; k < 4; ++k) {
        int ee = e[k];
        int r = atomicAdd(&lcur[ee], 1);            // LDS atomic (fast)
        unsigned idx = (unsigned)(lbase[ee] + r);
        if (idx < (unsigned)N_TOKENS) order[idx] = (unsigned short)(base + k * 256 + t);
    }
}

// Grouped GEMM, single kernel, runtime uniform branch on dtype flag.
// grid = (OUT_FEAT/BN, MAX_TILES): column-blocks of a tile are ADJACENT in
// dispatch order -> the 3 re-reads of each A-row hit LLC instead of HBM.
__global__ __launch_bounds__(256) void k_moe_gemm(
        const void* __restrict__ inp_,
        const void* __restrict__ weight_,
        void* __restrict__ out_,
        const int* __restrict__ ws) {
    __shared__ __align__(16) short sA[BM * SK];  // 9216 B, padded stride
    __shared__ __align__(16) short sB[BN * SK];  // 9216 B
    __shared__ int sTok[BM];

    int fp32 = ws[WS_FLAG];
    int ntiles = ws[WS_NTILES];
    if (ntiles > MAX_TILES) ntiles = MAX_TILES;
    int bx = blockIdx.y;
    if (bx >= ntiles) return;
    const int* tile = ws + WS_TILES + bx * 3;
    int e = tile[0] & 63;                      // defensive: in-bounds always
    int start = tile[1];
    int cnt = tile[2];
    cnt = cnt < 1 ? 1 : (cnt > BM ? BM : cnt);
    if (start < 0) start = 0;
    if (start > N_TOKENS - cnt) start = N_TOKENS - cnt;
    int n0 = blockIdx.x * BN;
    const unsigned short* order = (const unsigned short*)(ws + WS_ORDER);

    int tid = threadIdx.x;
    if (tid < BM) {
        int r = tid < cnt ? tid : (cnt - 1);
        sTok[tid] = (int)order[start + r];     // ushort -> always in [0,65535]
    }
    __syncthreads();

    int lane = tid & 63;
    int w = tid >> 6;
    int wm = (w >> 1) * 64;
    int wn = (w & 1) * 64;
    int l15 = lane & 15;
    int quad = lane >> 4;

    f32x4 acc[4][4];
    #pragma unroll
    for (int i = 0; i < 4; ++i)
        #pragma unroll
        for (int j = 0; j < 4; ++j)
            acc[i][j] = (f32x4){0.f, 0.f, 0.f, 0.f};

    // bank check (stride SK=36 shorts = 72 B): ds_read_b128 lane (l15,quad)
    // hits banks (18*l15 + 4*quad + d) mod 32 -> every bank exactly 2x = free.
    const short* sAr = &sA[(wm + l15) * SK + quad * 8];
    const short* sBr = &sB[(wn + l15) * SK + quad * 8];

    if (fp32) {
        // staging: thread -> row ra (0..127), half h; 16 floats -> 16 bf16
        int ra = tid >> 1;
        int h = tid & 1;
        int tokA = sTok[ra];
        const float4* aG = (const float4*)((const float*)inp_ + (size_t)tokA * IN_FEAT) + h * 4;
        const float4* bG = (const float4*)((const float*)weight_ +
                           (size_t)(e * OUT_FEAT + n0 + ra) * IN_FEAT) + h * 4;
        uint4* sAd = (uint4*)&sA[ra * SK + h * 16];
        uint4* sBd = (uint4*)&sB[ra * SK + h * 16];

        // register prefetch pipeline: loads for step ks+1 issued before MFMA(ks)
        float4 a0 = aG[0], a1 = aG[1], a2 = aG[2], a3 = aG[3];
        float4 b0 = bG[0], b1 = bG[1], b2 = bG[2], b3 = bG[3];
        aG += 8; bG += 8;
        for (int ks = 0; ks < K_STEPS; ++ks) {
            __syncthreads();
            sAd[0] = (uint4){pk2(a0.x, a0.y), pk2(a0.z, a0.w), pk2(a1.x, a1.y), pk2(a1.z, a1.w)};
            sAd[1] = (uint4){pk2(a2.x, a2.y), pk2(a2.z, a2.w), pk2(a3.x, a3.y), pk2(a3.z, a3.w)};
            sBd[0] = (uint4){pk2(b0.x, b0.y), pk2(b0.z, b0.w), pk2(b1.x, b1.y), pk2(b1.z, b1.w)};
            sBd[1] = (uint4){pk2(b2.x, b2.y), pk2(b2.z, b2.w), pk2(b3.x, b3.y), pk2(b3.z, b3.w)};
            __syncthreads();
            if (ks + 1 < K_STEPS) {
                a0 = aG[0]; a1 = aG[1]; a2 = aG[2]; a3 = aG[3];
                b0 = bG[0]; b1 = bG[1]; b2 = bG[2]; b3 = bG[3];
                aG += 8; bG += 8;
            }

            bf16x8 a[4], b[4];
            #pragma unroll
            for (int t = 0; t < 4; ++t) {
                a[t] = *(const bf16x8*)(sAr + t * 16 * SK);
                b[t] = *(const bf16x8*)(sBr + t * 16 * SK);
            }
            #pragma unroll
            for (int i = 0; i < 4; ++i)
                #pragma unroll
                for (int j = 0; j < 4; ++j)
                    acc[i][j] = __builtin_amdgcn_mfma_f32_16x16x32_bf16(a[i], b[j], acc[i][j], 0, 0, 0);
        }
    } else {
        // staging: thread -> 16B chunk qc of rows rr and rr+64
        int rr = tid >> 2;
        int qc = tid & 3;
        int tokA0 = sTok[rr];
        int tokA1 = sTok[rr + 64];
        const uint4* aG0 = (const uint4*)((const short*)inp_ + (size_t)tokA0 * IN_FEAT) + qc;
        const uint4* aG1 = (const uint4*)((const short*)inp_ + (size_t)tokA1 * IN_FEAT) + qc;
        const uint4* bG0 = (const uint4*)((const short*)weight_ +
                           (size_t)(e * OUT_FEAT + n0 + rr) * IN_FEAT) + qc;
        const uint4* bG1 = (const uint4*)((const short*)weight_ +
                           (size_t)(e * OUT_FEAT + n0 + rr + 64) * IN_FEAT) + qc;
        uint4* sAd0 = (uint4*)&sA[rr * SK + qc * 8];
        uint4* sAd1 = (uint4*)&sA[(rr + 64) * SK + qc * 8];
        uint4* sBd0 = (uint4*)&sB[rr * SK + qc * 8];
        uint4* sBd1 = (uint4*)&sB[(rr + 64) * SK + qc * 8];

        uint4 va0 = *aG0, va1 = *aG1, vb0 = *bG0, vb1 = *bG1;
        aG0 += 4; aG1 += 4; bG0 += 4; bG1 += 4;
        for (int ks = 0; ks < K_STEPS; ++ks) {
            __syncthreads();
            *sAd0 = va0; *sAd1 = va1; *sBd0 = vb0; *sBd1 = vb1;
            __syncthreads();
            if (ks + 1 < K_STEPS) {
                va0 = *aG0; va1 = *aG1; vb0 = *bG0; vb1 = *bG1;
                aG0 += 4; aG1 += 4; bG0 += 4; bG1 += 4;
            }

            bf16x8 a[4], b[4];
            #pragma unroll
            for (int t = 0; t < 4; ++t) {
                a[t] = *(const bf16x8*)(sAr + t * 16 * SK);
                b[t] = *(const bf16x8*)(sBr + t * 16 * SK);
            }
            #pragma unroll
            for (int i = 0; i < 4; ++i)
                #pragma unroll
                for (int j = 0; j < 4; ++j)
                    acc[i][j] = __builtin_amdgcn_mfma_f32_16x16x32_bf16(a[i], b[j], acc[i][j], 0, 0, 0);
        }
    }

    // epilogue: D col = lane&15, row = quad*4 + reg  [m89/m91]
    // Non-temporal stores: out (134 MB) must not evict inp+weight (201 MB) from LLC.
    #pragma unroll
    for (int i = 0; i < 4; ++i) {
        int mb = wm + i * 16 + quad * 4;
        #pragma unroll
        for (int r = 0; r < 4; ++r) {
            int m = mb + r;
            if (m < cnt) {
                int tok = sTok[m];
                if (fp32) {
                    float* orow = (float*)out_ + (size_t)tok * OUT_FEAT + n0 + wn + l15;
                    #pragma unroll
                    for (int j = 0; j < 4; ++j)
                        __builtin_nontemporal_store(acc[i][j][r], orow + j * 16);
                } else {
                    unsigned short* orow = (unsigned short*)out_ + (size_t)tok * OUT_FEAT + n0 + wn + l15;
                    #pragma unroll
                    for (int j = 0; j < 4; ++j)
                        __builtin_nontemporal_store(f2bu(acc[i][j][r]), orow + j * 16);
                }
            }
        }
    }
}

// ws-light fallback: one block per token, VALU dot products (only if ws too small)
__global__ __launch_bounds__(256) void k_gemv(
        const void* __restrict__ inp_,
        const int* __restrict__ gate,
        const void* __restrict__ weight_,
        void* __restrict__ out_,
        const int* __restrict__ ws) {
    int fp32 = ws[WS_FLAG];
    __shared__ float xf[IN_FEAT];
    int t = threadIdx.x;
    int tok = blockIdx.x;
    int e = gate[tok] & 63;
    if (fp32) {
        const float* xr = (const float*)inp_ + (size_t)tok * IN_FEAT;
        xf[2 * t] = xr[2 * t];
        xf[2 * t + 1] = xr[2 * t + 1];
        __syncthreads();
        #pragma unroll
        for (int rep = 0; rep < 2; ++rep) {
            int o = t + rep * 256;
            float s = 0.f;
            const float4* wr = (const float4*)((const float*)weight_ +
                               (size_t)(e * OUT_FEAT + o) * IN_FEAT);
            for (int k4 = 0; k4 < IN_FEAT / 4; ++k4) {
                float4 q = wr[k4];
                s += xf[4 * k4] * q.x + xf[4 * k4 + 1] * q.y
                   + xf[4 * k4 + 2] * q.z + xf[4 * k4 + 3] * q.w;
            }
            ((float*)out_)[(size_t)tok * OUT_FEAT + o] = s;
        }
    } else {
        const short* xr = (const short*)inp_ + (size_t)tok * IN_FEAT;
        xf[2 * t] = b2f(xr[2 * t]);
        xf[2 * t + 1] = b2f(xr[2 * t + 1]);
        __syncthreads();
        #pragma unroll
        for (int rep = 0; rep < 2; ++rep) {
            int o = t + rep * 256;
            float s = 0.f;
            const short4* wr = (const short4*)((const short*)weight_ +
                               (size_t)(e * OUT_FEAT + o) * IN_FEAT);
            for (int k4 = 0; k4 < IN_FEAT / 4; ++k4) {
                short4 q = wr[k4];
                s += xf[4 * k4] * b2f(q.x) + xf[4 * k4 + 1] * b2f(q.y)
                   + xf[4 * k4 + 2] * b2f(q.z) + xf[4 * k4 + 3] * b2f(q.w);
            }
            ((__hip_bfloat16*)out_)[(size_t)tok * OUT_FEAT + o] = __float2bfloat16(s);
        }
    }
}

extern "C" void kernel_launch(void* const* d_in, const int* in_sizes, int n_in,
                              void* d_out, int out_size, void* d_ws, size_t ws_size,
                              hipStream_t stream) {
    const void* inp    = d_in[0];
    const int*  gate   = (const int*)d_in[1];
    const void* weight = d_in[2];
    int* ws = (int*)d_ws;

    k_setup<<<1, 128, 0, stream>>>((const unsigned*)inp, ws);
    if (ws_size >= (size_t)WS_NEEDED) {
        k_hist<<<64, 256, 0, stream>>>(gate, ws);
        k_scan<<<1, 64, 0, stream>>>(ws);
        k_scatter<<<64, 256, 0, stream>>>(gate, ws);
        dim3 grid(OUT_FEAT / BN, MAX_TILES);   // ny fastest -> LLC locality for A rows
        k_moe_gemm<<<grid, 256, 0, stream>>>(inp, weight, d_out, ws);
    } else {
        k_gemv<<<N_TOKENS, 256, 0, stream>>>(inp, gate, weight, d_out, ws);
    }
}

// Round 2
// 366.159 us; speedup vs baseline: 1.3213x; 1.1556x over previous
//
#include <hip/hip_runtime.h>
#include <hip/hip_bf16.h>
#include <stdint.h>

#define N_TOKENS   65536
#define IN_FEAT    512
#define OUT_FEAT   512
#define NUM_EXPERT 64
#define BM 128
#define BN 128
#define BK 32
#define SK 36                    // padded LDS stride (mid-path kernel only)
#define K_STEPS (IN_FEAT / BK)   // 16
#define MAX_TILES 640            // true worst case: 512 + 64 = 576 tiles
#define NCOL (OUT_FEAT / BN)     // 4

// ws layout (int32 units), meta footprint 139264 bytes (as before):
//   [0..63] counts  [64..127] cursors  [128..192] offsets  [196] dtype flag
//   [197] tile_count  [200..1928) tiles  [2048..) order ushort[65536]
// BIG extension (byte offsets):
//   [147456 ..)                bf16 copy of inp   (67,108,864 B)
//   [147456+2*INP_ELEMS ..)    bf16 copy of weight (33,554,432 B)
#define WS_OFFS   128
#define WS_FLAG   196
#define WS_NTILES 197
#define WS_TILES  200
#define WS_ORDER  2048
#define WS_NEEDED (2048 * 4 + 131072)

#define INP_ELEMS (N_TOKENS * IN_FEAT)               // 33,554,432
#define W_ELEMS   (NUM_EXPERT * OUT_FEAT * IN_FEAT)  // 16,777,216
#define WS_BF16_OFF 147456
#define WS_BIG ((size_t)WS_BF16_OFF + 2ull * INP_ELEMS + 2ull * W_ELEMS)  // ~100.8 MB
#define CVT_BLKS 2048

typedef __attribute__((ext_vector_type(8))) short bf16x8;
typedef __attribute__((ext_vector_type(4))) float f32x4;

__device__ __forceinline__ float b2f(short v) {
    union { float f; unsigned u; } z;
    z.u = ((unsigned)(unsigned short)v) << 16;
    return z.f;
}

__device__ __forceinline__ unsigned pk2(float a, float b) {
    union { __hip_bfloat16 h; unsigned short u; } x, y;
    x.h = __float2bfloat16(a);
    y.h = __float2bfloat16(b);
    return ((unsigned)y.u << 16) | (unsigned)x.u;
}

__device__ __forceinline__ unsigned short f2bu(float a) {
    union { __hip_bfloat16 h; unsigned short u; } x;
    x.h = __float2bfloat16(a);
    return x.u;
}

// async global->LDS, 16B per lane; LDS dest is wave-uniform base + lane*16
__device__ __forceinline__ void gll16(const void* g, short* l) {
    __builtin_amdgcn_global_load_lds(
        (const __attribute__((address_space(1))) unsigned*)g,
        (__attribute__((address_space(3))) unsigned*)l, 16, 0, 0);
}

// Fused: dtype-detect (1 wave) + zero counts/cursors.
__global__ void k_setup(const unsigned* __restrict__ inw, int* __restrict__ ws) {
    int t = threadIdx.x;  // 128 threads
    ws[t] = 0;            // counts + cursors (does NOT touch WS_FLAG)
    if (t < 64) {
        int cnt = 0;
        #pragma unroll
        for (int i = 0; i < 16; ++i) {
            unsigned u = inw[t * 16 + i];
            unsigned lo = u & 0xFFFFu;
            unsigned ec = (lo >> 7) & 0xFFu;   // bf16 exponent field of low half
            if (lo == 0u || (ec >= 90u && ec <= 131u)) cnt++;
        }
        #pragma unroll
        for (int d = 32; d > 0; d >>= 1) cnt += __shfl_down(cnt, d, 64);
        if (t == 0) ws[WS_FLAG] = (cnt >= 512) ? 0 : 1;  // bf16 ~1000/1024, fp32 ~170/1024
    }
}

// Role-split kernel: blocks 0..63 = gate histogram; blocks 64.. = fp32->bf16
// conversion of inp+weight into ws (only when flag==1). Normal (cache-allocating)
// stores so the bf16 operands are LLC-hot for the GEMM.
__global__ __launch_bounds__(256) void k_pre(const int* __restrict__ gate,
                                             const void* __restrict__ inp_,
                                             const void* __restrict__ weight_,
                                             int* __restrict__ ws) {
    int t = threadIdx.x;
    if (blockIdx.x < 64) {
        __shared__ int h[NUM_EXPERT];
        if (t < NUM_EXPERT) h[t] = 0;
        __syncthreads();
        int base = blockIdx.x * 1024;
        #pragma unroll
        for (int k = 0; k < 4; ++k) {
            int g = gate[base + k * 256 + t] & 63;
            atomicAdd(&h[g], 1);
        }
        __syncthreads();
        if (t < NUM_EXPERT) atomicAdd(&ws[t], h[t]);
        return;
    }
    if (ws[WS_FLAG] != 1) return;   // bf16 inputs: nothing to convert
    const float* inpf = (const float*)inp_;
    const float* wf   = (const float*)weight_;
    short* bi = (short*)((char*)ws + WS_BF16_OFF);
    short* bw = bi + INP_ELEMS;
    const long long NC = (long long)(INP_ELEMS + W_ELEMS) / 8;  // 8-float chunks
    long long idx = (long long)(blockIdx.x - 64) * 256 + t;
    for (long long c = idx; c < NC; c += (long long)CVT_BLKS * 256) {
        long long f = c * 8;
        const float4* s;
        uint4* d;
        if (f < INP_ELEMS) {
            s = (const float4*)(inpf + f);
            d = (uint4*)(bi + f);
        } else {
            long long g = f - INP_ELEMS;
            s = (const float4*)(wf + g);
            d = (uint4*)(bw + g);
        }
        float4 x = s[0], y = s[1];
        *d = (uint4){pk2(x.x, x.y), pk2(x.z, x.w), pk2(y.x, y.y), pk2(y.z, y.w)};
    }
}

// single wave: prefix-scan counts, build tile descriptor list
__global__ void k_scan(int* ws) {
    int e = threadIdx.x;  // 0..63
    int c = ws[e];
    int pc = c;
    #pragma unroll
    for (int d = 1; d < 64; d <<= 1) {
        int v = __shfl_up(pc, d, 64);
        if (e >= d) pc += v;
    }
    int off = pc - c;
    ws[WS_OFFS + e] = off;
    if (e == 63) ws[WS_OFFS + 64] = pc;

    int nt = (c + BM - 1) / BM;
    int tnt = nt;
    #pragma unroll
    for (int d = 1; d < 64; d <<= 1) {
        int v = __shfl_up(tnt, d, 64);
        if (e >= d) tnt += v;
    }
    int tbase = tnt - nt;
    for (int j = 0; j < nt; ++j) {
        int* t = ws + WS_TILES + (tbase + j) * 3;
        t[0] = e;
        t[1] = off + j * BM;
        int rem = c - j * BM;
        t[2] = rem < BM ? rem : BM;
    }
    if (e == 63) ws[WS_NTILES] = tnt;
}

// Block-aggregated scatter: one global atomic per (block, expert).
__global__ __launch_bounds__(256) void k_scatter(const int* __restrict__ gate,
                                                 int* __restrict__ ws) {
    __shared__ int lh[NUM_EXPERT];
    __shared__ int lbase[NUM_EXPERT];
    __shared__ int lcur[NUM_EXPERT];
    int* cursors = ws + 64;
    const int* offsets = ws + WS_OFFS;
    unsigned short* order = (unsigned short*)(ws + WS_ORDER);
    int t = threadIdx.x;
    if (t < NUM_EXPERT) { lh[t] = 0; lcur[t] = 0; }
    __syncthreads();
    int base = blockIdx.x * 1024;
    int e[4];
    #pragma unroll
    for (int k = 0; k < 4; ++k) {
        e[k] = gate[base + k * 256 + t] & 63;
        atomicAdd(&lh[e[k]], 1);
    }
    __syncthreads();
    if (t < NUM_EXPERT) {
        int c = lh[t];
        int b = c ? atomicAdd(&cursors[t], c) : 0;
        lbase[t] = offsets[t] + b;
    }
    __syncthreads();
    #pragma unroll
    for (int k = 0; k < 4; ++k) {
        int ee = e[k];
        int r = atomicAdd(&lcur[ee], 1);
        unsigned idx = (unsigned)(lbase[ee] + r);
        if (idx < (unsigned)N_TOKENS) order[idx] = (unsigned short)(base + k * 256 + t);
    }
}

// ---------- BIG path: pure-bf16 grouped GEMM, global_load_lds staging ----------
// Persistent grid (2048 blocks = 8/CU residency) looping items = tile*4 + col.
// LDS layout is LINEAR (required by global_load_lds); bank conflicts fixed by
// swizzling the 16B chunk on the GLOBAL source side and reading with the same
// XOR (rule #21: both-sides-or-neither). chunk' = chunk ^ ((row>>1)&3) gives
// exactly 2 lanes/bank on ds_read_b128 (free).
__global__ __launch_bounds__(256) void k_moe_gemm_big(
        const void* __restrict__ inp_,
        const void* __restrict__ weight_,
        void* __restrict__ out_,
        const int* __restrict__ ws) {
    __shared__ __align__(16) short sA[BM * BK];  // 8 KB linear
    __shared__ __align__(16) short sB[BN * BK];  // 8 KB linear
    __shared__ int sTok[BM];

    int flag = ws[WS_FLAG];
    int ntiles = ws[WS_NTILES];
    if (ntiles > MAX_TILES) ntiles = MAX_TILES;
    int items = ntiles * NCOL;
    const unsigned short* order = (const unsigned short*)(ws + WS_ORDER);

    const short* Ab = flag ? (const short*)((const char*)ws + WS_BF16_OFF)
                           : (const short*)inp_;
    const short* Wb = flag ? (const short*)((const char*)ws + WS_BF16_OFF) + INP_ELEMS
                           : (const short*)weight_;

    int tid = threadIdx.x;
    int lane = tid & 63;
    int w = tid >> 6;
    int wm = (w >> 1) * 64;
    int wn = (w & 1) * 64;
    int l15 = lane & 15;
    int quad = lane >> 4;

    // frag read addresses (constant per thread): row-major linear + XOR chunk
    int rowA = wm + l15;
    const short* sAr = &sA[rowA * BK + (quad ^ ((rowA >> 1) & 3)) * 8];
    int rowB = wn + l15;
    const short* sBr = &sB[rowB * BK + (quad ^ ((rowB >> 1) & 3)) * 8];

    // staging lane roles: wave w stages 1KB segments {2w, 2w+1} of both A and B;
    // lane covers row r = seg*16 + (lane>>2), chunk c_lds = lane&3
    int sr = lane >> 2;
    int cl = lane & 3;
    int rS0 = w * 32 + sr;        // seg 2w
    int rS1 = rS0 + 16;           // seg 2w+1
    int cg0 = cl ^ ((rS0 >> 1) & 3);
    int cg1 = cl ^ ((rS1 >> 1) & 3);
    short* dA0 = &sA[(w * 2 + 0) * 512];
    short* dA1 = &sA[(w * 2 + 1) * 512];
    short* dB0 = &sB[(w * 2 + 0) * 512];
    short* dB1 = &sB[(w * 2 + 1) * 512];

    for (int item = blockIdx.x; item < items; item += gridDim.x) {
        int tIdx = item >> 2;
        int n0 = (item & 3) * BN;
        const int* tile = ws + WS_TILES + tIdx * 3;
        int e = tile[0] & 63;
        int start = tile[1];
        int cnt = tile[2];
        cnt = cnt < 1 ? 1 : (cnt > BM ? BM : cnt);
        if (start < 0) start = 0;
        if (start > N_TOKENS - cnt) start = N_TOKENS - cnt;

        __syncthreads();   // protect sTok/sA/sB reuse across items
        if (tid < BM) {
            int r = tid < cnt ? tid : (cnt - 1);
            sTok[tid] = (int)order[start + r];
        }
        __syncthreads();

        const char* gA0 = (const char*)(Ab + (size_t)sTok[rS0] * IN_FEAT) + cg0 * 16;
        const char* gA1 = (const char*)(Ab + (size_t)sTok[rS1] * IN_FEAT) + cg1 * 16;
        size_t wbase = (size_t)e * OUT_FEAT * IN_FEAT;
        const char* gB0 = (const char*)(Wb + wbase + (size_t)(n0 + rS0) * IN_FEAT) + cg0 * 16;
        const char* gB1 = (const char*)(Wb + wbase + (size_t)(n0 + rS1) * IN_FEAT) + cg1 * 16;

        f32x4 acc[4][4];
        #pragma unroll
        for (int i = 0; i < 4; ++i)
            #pragma unroll
            for (int j = 0; j < 4; ++j)
                acc[i][j] = (f32x4){0.f, 0.f, 0.f, 0.f};

        for (int ks = 0; ks < K_STEPS; ++ks) {
            __syncthreads();           // prev frag reads done -> safe to overwrite
            gll16(gA0, dA0);
            gll16(gA1, dA1);
            gll16(gB0, dB0);
            gll16(gB1, dB1);
            gA0 += 64; gA1 += 64; gB0 += 64; gB1 += 64;
            __syncthreads();           // implicit vmcnt(0) drain -> LDS ready

            bf16x8 a[4], b[4];
            #pragma unroll
            for (int t = 0; t < 4; ++t) {
                a[t] = *(const bf16x8*)(sAr + t * 16 * BK);
                b[t] = *(const bf16x8*)(sBr + t * 16 * BK);
            }
            #pragma unroll
            for (int i = 0; i < 4; ++i)
                #pragma unroll
                for (int j = 0; j < 4; ++j)
                    acc[i][j] = __builtin_amdgcn_mfma_f32_16x16x32_bf16(a[i], b[j], acc[i][j], 0, 0, 0);
        }

        // epilogue: D col = lane&15, row = quad*4 + reg [m89/m91]; NT stores keep
        // the bf16 operands resident in LLC.
        #pragma unroll
        for (int i = 0; i < 4; ++i) {
            int mb = wm + i * 16 + quad * 4;
            #pragma unroll
            for (int r = 0; r < 4; ++r) {
                int m = mb + r;
                if (m < cnt) {
                    int tok = sTok[m];
                    if (flag) {
                        float* orow = (float*)out_ + (size_t)tok * OUT_FEAT + n0 + wn + l15;
                        #pragma unroll
                        for (int j = 0; j < 4; ++j)
                            __builtin_nontemporal_store(acc[i][j][r], orow + j * 16);
                    } else {
                        unsigned short* orow = (unsigned short*)out_ + (size_t)tok * OUT_FEAT + n0 + wn + l15;
                        #pragma unroll
                        for (int j = 0; j < 4; ++j)
                            __builtin_nontemporal_store(f2bu(acc[i][j][r]), orow + j * 16);
                    }
                }
            }
        }
    }
}

// ---------- MID path (ws fits meta only): round-0 load ordering (VGPR ~64),
// SK-padded LDS, grid swap, NT stores ----------
__global__ __launch_bounds__(256) void k_moe_gemm_mid(
        const void* __restrict__ inp_,
        const void* __restrict__ weight_,
        void* __restrict__ out_,
        const int* __restrict__ ws) {
    __shared__ __align__(16) short sA[BM * SK];
    __shared__ __align__(16) short sB[BN * SK];
    __shared__ int sTok[BM];

    int fp32 = ws[WS_FLAG];
    int ntiles = ws[WS_NTILES];
    if (ntiles > MAX_TILES) ntiles = MAX_TILES;
    int bx = blockIdx.y;
    if (bx >= ntiles) return;
    const int* tile = ws + WS_TILES + bx * 3;
    int e = tile[0] & 63;
    int start = tile[1];
    int cnt = tile[2];
    cnt = cnt < 1 ? 1 : (cnt > BM ? BM : cnt);
    if (start < 0) start = 0;
    if (start > N_TOKENS - cnt) start = N_TOKENS - cnt;
    int n0 = blockIdx.x * BN;
    const unsigned short* order = (const unsigned short*)(ws + WS_ORDER);

    int tid = threadIdx.x;
    if (tid < BM) {
        int r = tid < cnt ? tid : (cnt - 1);
        sTok[tid] = (int)order[start + r];
    }
    __syncthreads();

    int lane = tid & 63;
    int w = tid >> 6;
    int wm = (w >> 1) * 64;
    int wn = (w & 1) * 64;
    int l15 = lane & 15;
    int quad = lane >> 4;

    f32x4 acc[4][4];
    #pragma unroll
    for (int i = 0; i < 4; ++i)
        #pragma unroll
        for (int j = 0; j < 4; ++j)
            acc[i][j] = (f32x4){0.f, 0.f, 0.f, 0.f};

    const short* sAr = &sA[(wm + l15) * SK + quad * 8];
    const short* sBr = &sB[(wn + l15) * SK + quad * 8];

    if (fp32) {
        int ra = tid >> 1;
        int h = tid & 1;
        int tokA = sTok[ra];
        const float4* aG = (const float4*)((const float*)inp_ + (size_t)tokA * IN_FEAT) + h * 4;
        const float4* bG = (const float4*)((const float*)weight_ +
                           (size_t)(e * OUT_FEAT + n0 + ra) * IN_FEAT) + h * 4;
        uint4* sAd = (uint4*)&sA[ra * SK + h * 16];
        uint4* sBd = (uint4*)&sB[ra * SK + h * 16];

        for (int ks = 0; ks < K_STEPS; ++ks) {
            float4 a0 = aG[0], a1 = aG[1], a2 = aG[2], a3 = aG[3];
            float4 b0 = bG[0], b1 = bG[1], b2 = bG[2], b3 = bG[3];
            aG += 8; bG += 8;
            __syncthreads();
            sAd[0] = (uint4){pk2(a0.x, a0.y), pk2(a0.z, a0.w), pk2(a1.x, a1.y), pk2(a1.z, a1.w)};
            sAd[1] = (uint4){pk2(a2.x, a2.y), pk2(a2.z, a2.w), pk2(a3.x, a3.y), pk2(a3.z, a3.w)};
            sBd[0] = (uint4){pk2(b0.x, b0.y), pk2(b0.z, b0.w), pk2(b1.x, b1.y), pk2(b1.z, b1.w)};
            sBd[1] = (uint4){pk2(b2.x, b2.y), pk2(b2.z, b2.w), pk2(b3.x, b3.y), pk2(b3.z, b3.w)};
            __syncthreads();

            bf16x8 a[4], b[4];
            #pragma unroll
            for (int t = 0; t < 4; ++t) {
                a[t] = *(const bf16x8*)(sAr + t * 16 * SK);
                b[t] = *(const bf16x8*)(sBr + t * 16 * SK);
            }
            #pragma unroll
            for (int i = 0; i < 4; ++i)
                #pragma unroll
                for (int j = 0; j < 4; ++j)
                    acc[i][j] = __builtin_amdgcn_mfma_f32_16x16x32_bf16(a[i], b[j], acc[i][j], 0, 0, 0);
        }
    } else {
        int rr = tid >> 2;
        int qc = tid & 3;
        int tokA0 = sTok[rr];
        int tokA1 = sTok[rr + 64];
        const uint4* aG0 = (const uint4*)((const short*)inp_ + (size_t)tokA0 * IN_FEAT) + qc;
        const uint4* aG1 = (const uint4*)((const short*)inp_ + (size_t)tokA1 * IN_FEAT) + qc;
        const uint4* bG0 = (const uint4*)((const short*)weight_ +
                           (size_t)(e * OUT_FEAT + n0 + rr) * IN_FEAT) + qc;
        const uint4* bG1 = (const uint4*)((const short*)weight_ +
                           (size_t)(e * OUT_FEAT + n0 + rr + 64) * IN_FEAT) + qc;
        uint4* sAd0 = (uint4*)&sA[rr * SK + qc * 8];
        uint4* sAd1 = (uint4*)&sA[(rr + 64) * SK + qc * 8];
        uint4* sBd0 = (uint4*)&sB[rr * SK + qc * 8];
        uint4* sBd1 = (uint4*)&sB[(rr + 64) * SK + qc * 8];

        for (int ks = 0; ks < K_STEPS; ++ks) {
            uint4 va0 = *aG0, va1 = *aG1, vb0 = *bG0, vb1 = *bG1;
            aG0 += 4; aG1 += 4; bG0 += 4; bG1 += 4;
            __syncthreads();
            *sAd0 = va0; *sAd1 = va1; *sBd0 = vb0; *sBd1 = vb1;
            __syncthreads();

            bf16x8 a[4], b[4];
            #pragma unroll
            for (int t = 0; t < 4; ++t) {
                a[t] = *(const bf16x8*)(sAr + t * 16 * SK);
                b[t] = *(const bf16x8*)(sBr + t * 16 * SK);
            }
            #pragma unroll
            for (int i = 0; i < 4; ++i)
                #pragma unroll
                for (int j = 0; j < 4; ++j)
                    acc[i][j] = __builtin_amdgcn_mfma_f32_16x16x32_bf16(a[i], b[j], acc[i][j], 0, 0, 0);
        }
    }

    #pragma unroll
    for (int i = 0; i < 4; ++i) {
        int mb = wm + i * 16 + quad * 4;
        #pragma unroll
        for (int r = 0; r < 4; ++r) {
            int m = mb + r;
            if (m < cnt) {
                int tok = sTok[m];
                if (fp32) {
                    float* orow = (float*)out_ + (size_t)tok * OUT_FEAT + n0 + wn + l15;
                    #pragma unroll
                    for (int j = 0; j < 4; ++j)
                        __builtin_nontemporal_store(acc[i][j][r], orow + j * 16);
                } else {
                    unsigned short* orow = (unsigned short*)out_ + (size_t)tok * OUT_FEAT + n0 + wn + l15;
                    #pragma unroll
                    for (int j = 0; j < 4; ++j)
                        __builtin_nontemporal_store(f2bu(acc[i][j][r]), orow + j * 16);
                }
            }
        }
    }
}

// ws-light fallback: one block per token, VALU dot products
__global__ __launch_bounds__(256) void k_gemv(
        const void* __restrict__ inp_,
        const int* __restrict__ gate,
        const void* __restrict__ weight_,
        void* __restrict__ out_,
        const int* __restrict__ ws) {
    int fp32 = ws[WS_FLAG];
    __shared__ float xf[IN_FEAT];
    int t = threadIdx.x;
    int tok = blockIdx.x;
    int e = gate[tok] & 63;
    if (fp32) {
        const float* xr = (const float*)inp_ + (size_t)tok * IN_FEAT;
        xf[2 * t] = xr[2 * t];
        xf[2 * t + 1] = xr[2 * t + 1];
        __syncthreads();
        #pragma unroll
        for (int rep = 0; rep < 2; ++rep) {
            int o = t + rep * 256;
            float s = 0.f;
            const float4* wr = (const float4*)((const float*)weight_ +
                               (size_t)(e * OUT_FEAT + o) * IN_FEAT);
            for (int k4 = 0; k4 < IN_FEAT / 4; ++k4) {
                float4 q = wr[k4];
                s += xf[4 * k4] * q.x + xf[4 * k4 + 1] * q.y
                   + xf[4 * k4 + 2] * q.z + xf[4 * k4 + 3] * q.w;
            }
            ((float*)out_)[(size_t)tok * OUT_FEAT + o] = s;
        }
    } else {
        const short* xr = (const short*)inp_ + (size_t)tok * IN_FEAT;
        xf[2 * t] = b2f(xr[2 * t]);
        xf[2 * t + 1] = b2f(xr[2 * t + 1]);
        __syncthreads();
        #pragma unroll
        for (int rep = 0; rep < 2; ++rep) {
            int o = t + rep * 256;
            float s = 0.f;
            const short4* wr = (const short4*)((const short*)weight_ +
                               (size_t)(e * OUT_FEAT + o) * IN_FEAT);
            for (int k4 = 0; k4 < IN_FEAT / 4; ++k4) {
                short4 q = wr[k4];
                s += xf[4 * k4] * b2f(q.x) + xf[4 * k4 + 1] * b2f(q.y)
                   + xf[4 * k4 + 2] * b2f(q.z) + xf[4 * k4 + 3] * b2f(q.w);
            }
            ((__hip_bfloat16*)out_)[(size_t)tok * OUT_FEAT + o] = __float2bfloat16(s);
        }
    }
}

extern "C" void kernel_launch(void* const* d_in, const int* in_sizes, int n_in,
                              void* d_out, int out_size, void* d_ws, size_t ws_size,
                              hipStream_t stream) {
    const void* inp    = d_in[0];
    const int*  gate   = (const int*)d_in[1];
    const void* weight = d_in[2];
    int* ws = (int*)d_ws;

    k_setup<<<1, 128, 0, stream>>>((const unsigned*)inp, ws);
    if (ws_size >= WS_BIG) {
        k_pre<<<64 + CVT_BLKS, 256, 0, stream>>>(gate, inp, weight, ws);
        k_scan<<<1, 64, 0, stream>>>(ws);
        k_scatter<<<64, 256, 0, stream>>>(gate, ws);
        k_moe_gemm_big<<<2048, 256, 0, stream>>>(inp, weight, d_out, ws);
    } else if (ws_size >= (size_t)WS_NEEDED) {
        k_pre<<<64, 256, 0, stream>>>(gate, inp, weight, ws);  // hist only
        k_scan<<<1, 64, 0, stream>>>(ws);
        k_scatter<<<64, 256, 0, stream>>>(gate, ws);
        dim3 grid(NCOL, MAX_TILES);
        k_moe_gemm_mid<<<grid, 256, 0, stream>>>(inp, weight, d_out, ws);
    } else {
        k_gemv<<<N_TOKENS, 256, 0, stream>>>(inp, gate, weight, d_out, ws);
    }
}